// Round 11
// baseline (390.462 us; speedup 1.0000x reference)
//
#include <hip/hip_runtime.h>
#include <math.h>

// ---------------- problem constants ----------------
constexpr int kB = 4, kW = 2000, kI = 64, kS = 64, kT = 24, kU = 32, kUS = 2;
constexpr int kPER = kW + kI + kS + kU + 1;   // 2161 nodes per graph
constexpr int kN   = kB * kPER;               // 8644 nodes total
constexpr int kTxtPer  = kW + kS + kU + 1;    // 2097 text rows per graph
constexpr int kTxtRows = kB * kTxtPer;        // 8388 text rows
constexpr int kEmb = 300;
constexpr int kEmbPad = 320;
constexpr int kHid = 1024;
constexpr int kOut = 512;
constexpr int kCap = 256;                     // max gathered rows for sparse gat2
constexpr int kNcB = 1152;                    // gat B rows: 1024 f cols + 4 el + 4 er + 120 pad
constexpr int kNB  = kN / 4;                  // 2161 node-blocks (4 nodes each)
constexpr int kNBhi = (kNB + 1) / 2;          // 1081

typedef __attribute__((ext_vector_type(8))) short bf16x8;
typedef __attribute__((ext_vector_type(4))) float f32x4;
typedef __attribute__((ext_vector_type(2))) float f32x2;

__device__ __forceinline__ unsigned short f2bf(float f) {
  union { float f; unsigned int u; } x; x.f = f;
  unsigned int r = x.u + 0x7FFF + ((x.u >> 16) & 1);
  return (unsigned short)(r >> 16);
}
__device__ __forceinline__ float bf2f(unsigned short u) {
  union { unsigned int u; float f; } x; x.u = ((unsigned int)u) << 16;
  return x.f;
}
// unpack 2 bf16 (one u32) -> float2 {lo, hi}
__device__ __forceinline__ f32x2 bfpair(unsigned int u) {
  union { unsigned int ui[2]; f32x2 f; } x;
  x.ui[0] = u << 16;
  x.ui[1] = u & 0xFFFF0000u;
  return x.f;
}

// async global->LDS, 16B per lane. LDS dest is wave-uniform base + lane*16.
__device__ __forceinline__ void gl16(const unsigned short* g, unsigned short* l) {
  __builtin_amdgcn_global_load_lds(
      (const __attribute__((address_space(1))) void*)g,
      (__attribute__((address_space(3))) void*)l,
      16, 0, 0);
}

// ---------------- mega prep (round-11-proven structure, NO wal/war segment) ----------------
// segments: txW 320 | imW 2048 | g0 1024 | g1 1024 | g2 512 | imgcvt 512 |
//           sent 256 | rowmap 34 | zcnt 34 | zCimg 256 | zCg2 128 | zpad 60
__global__ __launch_bounds__(256) void k_prep0(
    const float* __restrict__ tx_w, unsigned short* __restrict__ o_tx,
    const float* __restrict__ im_w, unsigned short* __restrict__ o_im,
    const float* __restrict__ g0_w, unsigned short* __restrict__ o_g0,   // [kNcB][1024]
    const float* __restrict__ g1_w, unsigned short* __restrict__ o_g1,   // [kNcB][1024]
    const float* __restrict__ g2_w, unsigned short* __restrict__ o_g2,
    const float* __restrict__ img, unsigned short* __restrict__ o_img,
    const int* __restrict__ sents, const float* __restrict__ smask,
    const float* __restrict__ wemb, float* __restrict__ sent,
    int* __restrict__ rmt, int* __restrict__ rmi,
    int* __restrict__ cnt, float* __restrict__ Cimg, float* __restrict__ Cg2) {
  int b = blockIdx.x;
  int tid = threadIdx.x;
  int tx = tid & 31, ty = tid >> 5;

  const float* in = nullptr; unsigned short* out = nullptr; int K = 0, N = 0, Kpad = 0, nbx = 0;
  if (b < 320)                { in = tx_w; out = o_tx; K = kEmb; N = kHid; Kpad = kEmbPad; nbx = 32; }
  else if ((b -= 320) < 2048) { in = im_w; out = o_im; K = 2048; N = kHid; Kpad = 2048; nbx = 32; }
  else if ((b -= 2048) < 1024){ in = g0_w; out = o_g0; K = kHid; N = kHid; Kpad = kHid; nbx = 32; }
  else if ((b -= 1024) < 1024){ in = g1_w; out = o_g1; K = kHid; N = kHid; Kpad = kHid; nbx = 32; }
  else if ((b -= 1024) < 512) { in = g2_w; out = o_g2; K = kHid; N = kOut; Kpad = kHid; nbx = 16; }
  else if ((b -= 512) < 512) {
    int i = b * 1024 + tid * 4;
    float4 v = *(const float4*)(img + i);
    ushort4 o; o.x = f2bf(v.x); o.y = f2bf(v.y); o.z = f2bf(v.z); o.w = f2bf(v.w);
    *(ushort4*)(o_img + i) = o;
    return;
  } else if ((b -= 512) < 256) {
    // sentence masked mean
    __shared__ int idx[kT];
    __shared__ float mk[kT];
    __shared__ float s_cnt;
    if (tid < kT) { idx[tid] = sents[b * kT + tid]; mk[tid] = smask[b * kT + tid]; }
    __syncthreads();
    if (tid == 0) {
      float c = 0.f;
      for (int i = 0; i < kT; ++i) c += mk[i];
      s_cnt = (c == 0.f) ? 1.f : c;
    }
    __syncthreads();
    for (int d = tid; d < kEmb; d += 256) {
      float acc = 0.f;
      for (int i = 0; i < kT; ++i) acc += wemb[idx[i] * kEmb + d] * mk[i];
      sent[b * kEmb + d] = acc / s_cnt;
    }
    return;
  } else if ((b -= 256) < 34) {
    int i = b * 256 + tid;
    if (i < kTxtRows) {
      int g = i / kTxtPer, j = i - g * kTxtPer;
      int base = g * kPER;
      int node;
      if (j < kW)                 node = base + j;
      else if (j < kW + kS)       node = base + kW + kI + (j - kW);
      else if (j < kW + kS + kU)  node = base + kW + kI + kS + (j - kW - kS);
      else                        node = base + kW + kI + kS + kU;
      rmt[i] = node;
    }
    if (i < kB * kI) {
      int g = i >> 6;
      rmi[i] = g * kPER + kW + (i & 63);
    }
    return;
  } else if ((b -= 34) < 34) {
    int i = b * 256 + tid;
    if (i < kN) cnt[i] = 0;
    return;
  } else if ((b -= 34) < 256) {
    uint4 z = make_uint4(0u, 0u, 0u, 0u);
    ((uint4*)Cimg)[b * 256 + tid] = z;
    return;
  } else if ((b -= 256) < 128) {
    uint4 z = make_uint4(0u, 0u, 0u, 0u);
    ((uint4*)Cg2)[b * 256 + tid] = z;
    return;
  } else {
    // zero pad rows 1032..1151 of both extended gat weights (60 blocks)
    b -= 128;
    int i = b * 256 + tid;                 // 0..15359
    uint4 z = make_uint4(0u, 0u, 0u, 0u);
    ((uint4*)(o_g0 + (size_t)1032 * kHid))[i] = z;
    ((uint4*)(o_g1 + (size_t)1032 * kHid))[i] = z;
    return;
  }

  // transpose body (reached only for the 5 transpose segments)
  int bx = b % nbx, by = b / nbx;
  __shared__ float t[32][33];
  int n = bx * 32 + tx;
#pragma unroll
  for (int j = 0; j < 4; ++j) {
    int k = by * 32 + ty + j * 8;
    t[ty + j * 8][tx] = (k < K) ? in[(size_t)k * N + n] : 0.f;
  }
  __syncthreads();
#pragma unroll
  for (int j = 0; j < 4; ++j) {
    int nn = bx * 32 + ty + j * 8;
    int kk = by * 32 + tx;
    out[(size_t)nn * Kpad + kk] = f2bf(t[tx][ty + j * 8]);
  }
}

// ---------------- utt + sess + wal/war (parallel, off critical path) ----------------
// blocks: [0, kB*kU) utt | [kB*kU, kB*kU+kB) sess | [132, 132+256) wal/war
__global__ __launch_bounds__(256) void k_utt_sess(const int* __restrict__ utts,
                                                  const float* __restrict__ umask,
                                                  const float* __restrict__ sent,
                                                  float* __restrict__ utt,
                                                  float* __restrict__ sess,
                                                  const float* __restrict__ g0_w,
                                                  const float* __restrict__ g1_w,
                                                  const float* __restrict__ g0_al,
                                                  const float* __restrict__ g0_ar,
                                                  const float* __restrict__ g1_al,
                                                  const float* __restrict__ g1_ar,
                                                  unsigned short* __restrict__ o_g0,
                                                  unsigned short* __restrict__ o_g1) {
  int blk = blockIdx.x;
  int tid = threadIdx.x;
  if (blk < kB * kU) {
    int bu = blk, b = bu / kU;
    __shared__ int idx[kUS];
    __shared__ float mk[kUS];
    __shared__ float s_cnt;
    if (tid < kUS) { idx[tid] = utts[bu * kUS + tid]; mk[tid] = umask[bu * kUS + tid]; }
    __syncthreads();
    if (tid == 0) {
      float c = 0.f;
      for (int i = 0; i < kUS; ++i) c += mk[i];
      s_cnt = (c == 0.f) ? 1.f : c;
    }
    __syncthreads();
    for (int d = tid; d < kEmb; d += 256) {
      float acc = 0.f;
      for (int i = 0; i < kUS; ++i) acc += sent[(b * kS + idx[i]) * kEmb + d] * mk[i];
      utt[bu * kEmb + d] = acc / s_cnt;
    }
  } else if (blk < kB * kU + kB) {
    int b = blk - kB * kU;                // graph index
    for (int d = tid; d < kEmb; d += 256) {
      float acc = 0.f;
      for (int u = 0; u < kU; ++u) {
        float ua = 0.f, c = 0.f;
        for (int us = 0; us < kUS; ++us) {
          int i = (b * kU + u) * kUS + us;
          int sidx = utts[i];
          float m = umask[i];
          ua += sent[(b * kS + sidx) * kEmb + d] * m;
          c += m;
        }
        if (c == 0.f) c = 1.f;
        acc += ua / c;
      }
      sess[b * kEmb + d] = acc * (1.f / kU);
    }
  } else {
    // wal/war projections: 256 blocks, each handles 64 k's of one (layer,which,head,kblk).
    // wt[1024 + which*4 + h][k] = sum_d fc[k][h*256+d] * a[h*256+d]
    int b = blk - (kB * kU + kB);         // 0..255
    int layer = b >> 7, rem = b & 127;
    int which = rem >> 6;
    int rem2 = rem & 63;
    int h = rem2 >> 4, kblk = rem2 & 15;
    const float* fc = layer ? g1_w : g0_w;
    const float* a  = layer ? (which ? g1_ar : g1_al) : (which ? g0_ar : g0_al);
    unsigned short* wt = layer ? o_g1 : o_g0;
    int kl = tid >> 2, q = tid & 3;       // 64 k's per block, 4 threads per k
    int k = kblk * 64 + kl;
    float s = 0.f;
    const float* fr = fc + (size_t)k * kHid + h * 256 + q * 64;
    const float* av = a + h * 256 + q * 64;
    for (int d = 0; d < 64; ++d) s += fr[d] * av[d];
    s += __shfl_xor(s, 1);
    s += __shfl_xor(s, 2);
    if (q == 0) wt[(size_t)(1024 + which * 4 + h) * kHid + k] = f2bf(s);
  }
}

// ---------------- txt gather (bf16) + edge count fused ----------------
__global__ __launch_bounds__(256) void k_txtcount(const int* __restrict__ aw,
                                                  const float* __restrict__ wemb,
                                                  const float* __restrict__ sent,
                                                  const float* __restrict__ utt,
                                                  const float* __restrict__ sess,
                                                  unsigned short* __restrict__ txt,
                                                  const int* __restrict__ dst,
                                                  int* __restrict__ cnt, int E) {
  int blk = blockIdx.x;
  int tid = threadIdx.x;
  if (blk < kTxtRows) {
    int r = blk;
    int g = r / kTxtPer, j = r - g * kTxtPer;
    const float* src;
    if (j < kW)                 src = wemb + (size_t)aw[g * kW + j] * kEmb;
    else if (j < kW + kS)       src = sent + (size_t)(g * kS + (j - kW)) * kEmb;
    else if (j < kW + kS + kU)  src = utt  + (size_t)(g * kU + (j - kW - kS)) * kEmb;
    else                        src = sess + (size_t)g * kEmb;
    for (int d = tid; d < kEmbPad; d += 256)
      txt[(size_t)r * kEmbPad + d] = (d < kEmb) ? f2bf(src[d]) : (unsigned short)0;
  } else {
    int e = (blk - kTxtRows) * 256 + tid;
    if (e < E) atomicAdd(&cnt[dst[e]], 1);
  }
}

// ---------------- bf16 MFMA GEMM, XCD-banded 1-D grid, optional el/er cols ----------------
// staging via global_load_lds (linear LDS dest, inverse-swizzled global source).
// r6 structure: 128x128 tile, 32KB LDS, single buffer, 512 threads = 8 waves/block.
template <bool OBF, bool ELR>
__global__ __launch_bounds__(512) void k_mm2(const unsigned short* __restrict__ A,
                                             const unsigned short* __restrict__ Bt,
                                             const float* __restrict__ bias,
                                             const int* __restrict__ rmap,
                                             void* __restrict__ Cout,
                                             float* __restrict__ el,
                                             float* __restrict__ er,
                                             int M, int K, int NcB, int NcOut) {
  __shared__ __align__(16) unsigned short As[128 * 64];
  __shared__ __align__(16) unsigned short Bs[128 * 64];
  int nCol = NcB >> 7;
  int bi = blockIdx.x;
  int xcd = bi & 7, bj = bi >> 3;
  int colTile = bj % nCol;
  int rowTile = ((bj / nCol) << 3) + xcd;
  int row0 = rowTile << 7;
  if (row0 >= M) return;
  int col0 = colTile << 7;

  int tid = threadIdx.x;
  int wid = tid >> 6, lane = tid & 63, quad = lane >> 4, l16 = lane & 15;
  int wm = wid >> 1, wn = wid & 1;      // wave tile: 32M x 64N

  f32x4 acc[2][4];
  f32x4 zero4 = {0.f, 0.f, 0.f, 0.f};
#pragma unroll
  for (int i = 0; i < 2; ++i)
#pragma unroll
    for (int j = 0; j < 4; ++j) acc[i][j] = zero4;

  // lane -> (row-in-8, fetched chunk). LDS packet: wave writes 8 rows x 128B linearly;
  // lane l covers row (l>>3), byte-chunk (l&7). Source chunk = (l&7) ^ (l>>3) so that
  // LDS position c of row r holds global chunk c ^ (r&7)  (matches read-side swizzle).
  int lr = lane >> 3;
  int swc = (lane & 7) ^ lr;

  for (int k0 = 0; k0 < K; k0 += 64) {
    __syncthreads();
#pragma unroll
    for (int i = 0; i < 2; ++i) {       // 16 A-packets + 16 B-packets over 8 waves
      int rb = i * 64 + wid * 8;        // 8-row packet base (wave-uniform)
      int r = rb + lr;
      int grow = row0 + r;
      if (grow >= M) grow = row0;       // clamp: rows discarded in epilogue
      gl16(A + (size_t)grow * K + k0 + (swc << 3), &As[rb * 64]);
      int nrow = col0 + r;
      gl16(Bt + (size_t)nrow * K + k0 + (swc << 3), &Bs[rb * 64]);
    }
    __syncthreads();                    // drains vmcnt before barrier
#pragma unroll
    for (int s = 0; s < 2; ++s) {
      int cc = s * 4 + quad;
      bf16x8 aF[2], bF[4];
#pragma unroll
      for (int mi = 0; mi < 2; ++mi) {
        int r = wm * 32 + mi * 16 + l16;
        aF[mi] = *(const bf16x8*)&As[r * 64 + ((cc ^ (r & 7)) << 3)];
      }
#pragma unroll
      for (int ni = 0; ni < 4; ++ni) {
        int r = wn * 64 + ni * 16 + l16;
        bF[ni] = *(const bf16x8*)&Bs[r * 64 + ((cc ^ (r & 7)) << 3)];
      }
#pragma unroll
      for (int mi = 0; mi < 2; ++mi)
#pragma unroll
        for (int ni = 0; ni < 4; ++ni)
          acc[mi][ni] = __builtin_amdgcn_mfma_f32_16x16x32_bf16(aF[mi], bF[ni], acc[mi][ni], 0, 0, 0);
    }
  }

  // ---- epilogue (C/D layout: col=lane&15, row=quad*4+reg) ----
#pragma unroll
  for (int mi = 0; mi < 2; ++mi) {
#pragma unroll
    for (int ni = 0; ni < 4; ++ni) {
      int gm0 = row0 + wm * 32 + mi * 16 + quad * 4;
      int gn  = col0 + wn * 64 + ni * 16 + l16;
      float bv = (bias && gn < NcOut) ? bias[gn] : 0.f;
#pragma unroll
      for (int i = 0; i < 4; ++i) {
        int r = gm0 + i;
        if (r >= M) continue;
        float v = acc[mi][ni][i] + bv;
        if (gn < NcOut) {
          if (OBF) {
            int orow = rmap ? rmap[r] : r;
            ((unsigned short*)Cout)[(size_t)orow * NcOut + gn] = f2bf(v);
          } else {
            ((float*)Cout)[(size_t)r * NcOut + gn] = v;
          }
        } else if (ELR) {
          int gn2 = gn - NcOut;
          if (gn2 < 4)      el[r * 4 + gn2] = v;
          else if (gn2 < 8) er[r * 4 + gn2 - 4] = v;
        }
      }
    }
  }
}

// ---------------- split-K bf16 MFMA GEMM (64x64 tile, optional A-row gather) ----------------
__global__ __launch_bounds__(256) void k_mm_sk(const unsigned short* __restrict__ A,
                                               const unsigned short* __restrict__ Bt,
                                               const int* __restrict__ rowlist,
                                               float* __restrict__ C,
                                               int M, int K, int Nc, int Kc) {
  __shared__ __align__(16) unsigned short As[64 * 64];
  __shared__ __align__(16) unsigned short Bs[64 * 64];
  int tid = threadIdx.x;
  int wid = tid >> 6, lane = tid & 63, quad = lane >> 4, l16 = lane & 15;
  int row0 = blockIdx.y * 64, col0 = blockIdx.x * 64;
  int k0 = blockIdx.z * Kc;
  int k1 = k0 + Kc; if (k1 > K) k1 = K;

  f32x4 acc[4];
  f32x4 zero4 = {0.f, 0.f, 0.f, 0.f};
#pragma unroll
  for (int i = 0; i < 4; ++i) acc[i] = zero4;

  int lr = lane >> 3;
  int swc = (lane & 7) ^ lr;

  // hoist A row indices (gather) out of the K loop
  int arow[2];
#pragma unroll
  for (int i = 0; i < 2; ++i) {
    int grow = row0 + i * 32 + wid * 8 + lr;
    int ar = 0;
    if (grow < M) ar = rowlist ? rowlist[grow] : grow;
    arow[i] = ar;
  }

  for (int kk = k0; kk < k1; kk += 64) {
    __syncthreads();
#pragma unroll
    for (int i = 0; i < 2; ++i) {
      int rb = i * 32 + wid * 8;
      gl16(A + (size_t)arow[i] * K + kk + (swc << 3), &As[rb * 64]);
      int nrow = col0 + rb + lr;
      gl16(Bt + (size_t)nrow * K + kk + (swc << 3), &Bs[rb * 64]);
    }
    __syncthreads();
#pragma unroll
    for (int s = 0; s < 2; ++s) {
      int cc = s * 4 + quad;
      bf16x8 bF;
      {
        int r = wid * 16 + l16;
        bF = *(const bf16x8*)&Bs[r * 64 + ((cc ^ (r & 7)) << 3)];
      }
#pragma unroll
      for (int mi = 0; mi < 4; ++mi) {
        int r = mi * 16 + l16;
        bf16x8 aF = *(const bf16x8*)&As[r * 64 + ((cc ^ (r & 7)) << 3)];
        acc[mi] = __builtin_amdgcn_mfma_f32_16x16x32_bf16(aF, bF, acc[mi], 0, 0, 0);
      }
    }
  }
#pragma unroll
  for (int mi = 0; mi < 4; ++mi) {
#pragma unroll
    for (int i = 0; i < 4; ++i) {
      int r = row0 + mi * 16 + quad * 4 + i;
      int c = col0 + wid * 16 + l16;
      if (r < M) atomicAdd(&C[(size_t)r * Nc + c], acc[mi][i]);
    }
  }
}

__global__ void k_sk_epi(const float* __restrict__ Cw, const float* __restrict__ bias,
                         const int* __restrict__ rmap, unsigned short* __restrict__ out,
                         int M, int Nc) {
  int i = blockIdx.x * blockDim.x + threadIdx.x;
  if (i >= M * Nc) return;
  int r = i / Nc, c = i - r * Nc;
  out[(size_t)rmap[r] * Nc + c] = f2bf(Cw[i] + bias[c]);
}

// ---------------- CSR build ----------------
__global__ void k_scan(int* __restrict__ deg, int* __restrict__ offs, int n) {
  __shared__ int part[1024];
  int tid = threadIdx.x;
  int per = (n + 1023) >> 10;
  int start = tid * per;
  int local = 0;
  for (int i = 0; i < per; ++i) { int idx = start + i; if (idx < n) local += deg[idx]; }
  part[tid] = local;
  __syncthreads();
  for (int off = 1; off < 1024; off <<= 1) {
    int add = (tid >= off) ? part[tid - off] : 0;
    __syncthreads();
    part[tid] += add;
    __syncthreads();
  }
  int run = (tid == 0) ? 0 : part[tid - 1];
  for (int i = 0; i < per; ++i) {
    int idx = start + i;
    if (idx < n) { offs[idx] = run; run += deg[idx]; }
  }
  if (tid == 1023) offs[n] = part[1023];
  __syncthreads();
  for (int i = tid; i < n; i += 1024) deg[i] = 0;
}

__global__ void k_fill(const int* __restrict__ src, const int* __restrict__ dst,
                       const int* __restrict__ offs, int* __restrict__ cur,
                       int* __restrict__ csr, int E) {
  int e = blockIdx.x * blockDim.x + threadIdx.x;
  if (e < E) {
    int d = dst[e];
    int slot = offs[d] + atomicAdd(&cur[d], 1);
    csr[slot] = src[e];
  }
}

// ---------------- softmax weights: one wave per node, all 4 heads at once ----------------
// writes normalized weights head-major: wcsr[h*E + e]  (2.4 MB, L2-resident)
__global__ __launch_bounds__(256) void k_smaxw(const float* __restrict__ el,
                                               const float* __restrict__ er,
                                               const int* __restrict__ offs,
                                               const int* __restrict__ csr,
                                               float* __restrict__ wcsr, int E) {
  int tid = threadIdx.x;
  int wid = tid >> 6, lane = tid & 63;
  int v = blockIdx.x * 4 + wid;
  int e0 = offs[v];
  int deg = offs[v + 1] - e0;
  float4 erv = *(const float4*)(er + (size_t)v * 4);

  if (deg <= 64) {
    float x0 = -1e30f, x1 = -1e30f, x2 = -1e30f, x3 = -1e30f;
    if (lane < deg) {
      int s = csr[e0 + lane];
      float4 e4 = *(const float4*)(el + (size_t)s * 4);
      x0 = e4.x + erv.x; x1 = e4.y + erv.y; x2 = e4.z + erv.z; x3 = e4.w + erv.w;
      x0 = x0 > 0.f ? x0 : 0.2f * x0;
      x1 = x1 > 0.f ? x1 : 0.2f * x1;
      x2 = x2 > 0.f ? x2 : 0.2f * x2;
      x3 = x3 > 0.f ? x3 : 0.2f * x3;
    }
    float m0 = x0, m1 = x1, m2 = x2, m3 = x3;
#pragma unroll
    for (int o = 32; o; o >>= 1) {
      m0 = fmaxf(m0, __shfl_xor(m0, o));
      m1 = fmaxf(m1, __shfl_xor(m1, o));
      m2 = fmaxf(m2, __shfl_xor(m2, o));
      m3 = fmaxf(m3, __shfl_xor(m3, o));
    }
    float w0 = expf(x0 - m0), w1 = expf(x1 - m1);
    float w2 = expf(x2 - m2), w3 = expf(x3 - m3);
    float z0 = w0, z1 = w1, z2 = w2, z3 = w3;
#pragma unroll
    for (int o = 32; o; o >>= 1) {
      z0 += __shfl_xor(z0, o); z1 += __shfl_xor(z1, o);
      z2 += __shfl_xor(z2, o); z3 += __shfl_xor(z3, o);
    }
    if (lane < deg) {
      wcsr[(size_t)0 * E + e0 + lane] = w0 / z0;
      wcsr[(size_t)1 * E + e0 + lane] = w1 / z1;
      wcsr[(size_t)2 * E + e0 + lane] = w2 / z2;
      wcsr[(size_t)3 * E + e0 + lane] = w3 / z3;
    }
  } else {
    // rare path: 3 passes with reload
    float m0 = -1e30f, m1 = -1e30f, m2 = -1e30f, m3 = -1e30f;
    for (int base = 0; base < deg; base += 64) {
      int idx = base + lane;
      if (idx < deg) {
        int s = csr[e0 + idx];
        float4 e4 = *(const float4*)(el + (size_t)s * 4);
        float x0 = e4.x + erv.x, x1 = e4.y + erv.y, x2 = e4.z + erv.z, x3 = e4.w + erv.w;
        x0 = x0 > 0.f ? x0 : 0.2f * x0;
        x1 = x1 > 0.f ? x1 : 0.2f * x1;
        x2 = x2 > 0.f ? x2 : 0.2f * x2;
        x3 = x3 > 0.f ? x3 : 0.2f * x3;
        m0 = fmaxf(m0, x0); m1 = fmaxf(m1, x1);
        m2 = fmaxf(m2, x2); m3 = fmaxf(m3, x3);
      }
    }
#pragma unroll
    for (int o = 32; o; o >>= 1) {
      m0 = fmaxf(m0, __shfl_xor(m0, o));
      m1 = fmaxf(m1, __shfl_xor(m1, o));
      m2 = fmaxf(m2, __shfl_xor(m2, o));
      m3 = fmaxf(m3, __shfl_xor(m3, o));
    }
    float z0 = 0.f, z1 = 0.f, z2 = 0.f, z3 = 0.f;
    for (int base = 0; base < deg; base += 64) {
      int idx = base + lane;
      if (idx < deg) {
        int s = csr[e0 + idx];
        float4 e4 = *(const float4*)(el + (size_t)s * 4);
        float x0 = e4.x + erv.x, x1 = e4.y + erv.y, x2 = e4.z + erv.z, x3 = e4.w + erv.w;
        x0 = x0 > 0.f ? x0 : 0.2f * x0;
        x1 = x1 > 0.f ? x1 : 0.2f * x1;
        x2 = x2 > 0.f ? x2 : 0.2f * x2;
        x3 = x3 > 0.f ? x3 : 0.2f * x3;
        float w0 = expf(x0 - m0), w1 = expf(x1 - m1);
        float w2 = expf(x2 - m2), w3 = expf(x3 - m3);
        wcsr[(size_t)0 * E + e0 + idx] = w0;
        wcsr[(size_t)1 * E + e0 + idx] = w1;
        wcsr[(size_t)2 * E + e0 + idx] = w2;
        wcsr[(size_t)3 * E + e0 + idx] = w3;
        z0 += w0; z1 += w1; z2 += w2; z3 += w3;
      }
    }
#pragma unroll
    for (int o = 32; o; o >>= 1) {
      z0 += __shfl_xor(z0, o); z1 += __shfl_xor(z1, o);
      z2 += __shfl_xor(z2, o); z3 += __shfl_xor(z3, o);
    }
    float r0 = 1.f / z0, r1 = 1.f / z1, r2 = 1.f / z2, r3 = 1.f / z3;
    for (int base = 0; base < deg; base += 64) {
      int idx = base + lane;
      if (idx < deg) {
        wcsr[(size_t)0 * E + e0 + idx] *= r0;
        wcsr[(size_t)1 * E + e0 + idx] *= r1;
        wcsr[(size_t)2 * E + e0 + idx] *= r2;
        wcsr[(size_t)3 * E + e0 + idx] *= r3;
      }
    }
  }
}

// ---------------- scalar-uniform aggregation: wave = (node, head), XCD head-pinned --------
// grid = 8 * kNBhi. xcd = bid&7 -> head h = xcd&3, node half = xcd>>2. e0/deg in SGPR so
// csr/wcsr reads are s_load broadcasts. Round-11: half-wave edge parallelism — 32 lanes x
// 8 dims (uint4, 16B) cover one 256-dim row; the two wave halves process DIFFERENT edges.
// 8 edges per unrolled iter = 4 x 16B loads/lane in flight; cross-half shfl_xor(32) at end.
__global__ __launch_bounds__(256) void k_aggs(const unsigned short* __restrict__ f,
                                              const int* __restrict__ offs,
                                              const int* __restrict__ csr,
                                              const float* __restrict__ wcsr,
                                              const float* __restrict__ bias,
                                              unsigned short* __restrict__ out, int E) {
  int bid = blockIdx.x;
  int xcd = bid & 7;
  int h = xcd & 3;                        // head (L2-pinned per XCD pair)
  int nb = (xcd >> 2) * kNBhi + (bid >> 3);
  if (nb >= kNB) return;
  int tid = threadIdx.x;
  int wid = tid >> 6, lane = tid & 63;
  int v = nb * 4 + wid;                   // kN == kNB*4 exactly

  int e0 = __builtin_amdgcn_readfirstlane(offs[v]);
  int deg = __builtin_amdgcn_readfirstlane(offs[v + 1]) - e0;

  const int* cs = csr + e0;               // uniform base -> s_load stream
  const float* wp = wcsr + (size_t)h * E + e0;
  int half = lane >> 5, l32 = lane & 31;
  const unsigned short* fb = f + h * 256 + l32 * 8;   // 8 dims/lane, 32 lanes = full row

  f32x2 a0 = {0.f, 0.f}, a1 = {0.f, 0.f}, a2 = {0.f, 0.f}, a3 = {0.f, 0.f};
  f32x2 b0 = {0.f, 0.f}, b1 = {0.f, 0.f}, b2 = {0.f, 0.f}, b3 = {0.f, 0.f};
  int e = 0;
  for (; e + 8 <= deg; e += 8) {
    // j=0
    int sA0 = cs[e + 0], sB0 = cs[e + 4];
    float wA0 = wp[e + 0], wB0 = wp[e + 4];
    int s0 = half ? sB0 : sA0; float w0 = half ? wB0 : wA0;
    uint4 q0 = *(const uint4*)(fb + ((size_t)s0 << 10));
    // j=1
    int sA1 = cs[e + 1], sB1 = cs[e + 5];
    float wA1 = wp[e + 1], wB1 = wp[e + 5];
    int s1 = half ? sB1 : sA1; float w1 = half ? wB1 : wA1;
    uint4 q1 = *(const uint4*)(fb + ((size_t)s1 << 10));
    // j=2
    int sA2 = cs[e + 2], sB2 = cs[e + 6];
    float wA2 = wp[e + 2], wB2 = wp[e + 6];
    int s2 = half ? sB2 : sA2; float w2 = half ? wB2 : wA2;
    uint4 q2 = *(const uint4*)(fb + ((size_t)s2 << 10));
    // j=3
    int sA3 = cs[e + 3], sB3 = cs[e + 7];
    float wA3 = wp[e + 3], wB3 = wp[e + 7];
    int s3 = half ? sB3 : sA3; float w3 = half ? wB3 : wA3;
    uint4 q3 = *(const uint4*)(fb + ((size_t)s3 << 10));

    f32x2 wv0 = {w0, w0}, wv1 = {w1, w1}, wv2 = {w2, w2}, wv3 = {w3, w3};
    a0 += wv0 * bfpair(q0.x); a1 += wv0 * bfpair(q0.y);
    a2 += wv0 * bfpair(q0.z); a3 += wv0 * bfpair(q0.w);
    b0 += wv1 * bfpair(q1.x); b1 += wv1 * bfpair(q1.y);
    b2 += wv1 * bfpair(q1.z); b3 += wv1 * bfpair(q1.w);
    a0 += wv2 * bfpair(q2.x); a1 += wv2 * bfpair(q2.y);
    a2 += wv2 * bfpair(q2.z); a3 += wv2 * bfpair(q2.w);
    b0 += wv3 * bfpair(q3.x); b1 += wv3 * bfpair(q3.y);
    b2 += wv3 * bfpair(q3.z); b3 += wv3 * bfpair(q3.w);
  }
  for (; e < deg; e += 2) {
    int idx = e + half;
    int s = 0; float w = 0.f;
    if (idx < deg) { s = cs[idx]; w = wp[idx]; }
    uint4 q = *(const uint4*)(fb + ((size_t)s << 10));
    f32x2 wv = {w, w};
    a0 += wv * bfpair(q.x); a1 += wv * bfpair(q.y);
    a2 += wv * bfpair(q.z); a3 += wv * bfpair(q.w);
  }
  a0 += b0; a1 += b1; a2 += b2; a3 += b3;
  float r0 = a0.x, r1 = a0.y, r2 = a1.x, r3 = a1.y;
  float r4 = a2.x, r5 = a2.y, r6 = a3.x, r7 = a3.y;
  r0 += __shfl_xor(r0, 32); r1 += __shfl_xor(r1, 32);
  r2 += __shfl_xor(r2, 32); r3 += __shfl_xor(r3, 32);
  r4 += __shfl_xor(r4, 32); r5 += __shfl_xor(r5, 32);
  r6 += __shfl_xor(r6, 32); r7 += __shfl_xor(r7, 32);

  if (half == 0) {
    int dd = h * 256 + l32 * 8;
    float4 bv0 = *(const float4*)(bias + dd);
    float4 bv1 = *(const float4*)(bias + dd + 4);
    float o0 = r0 + bv0.x, o1 = r1 + bv0.y, o2 = r2 + bv0.z, o3 = r3 + bv0.w;
    float o4 = r4 + bv1.x, o5 = r5 + bv1.y, o6 = r6 + bv1.z, o7 = r7 + bv1.w;
    o0 = o0 > 0.f ? o0 : expm1f(o0);
    o1 = o1 > 0.f ? o1 : expm1f(o1);
    o2 = o2 > 0.f ? o2 : expm1f(o2);
    o3 = o3 > 0.f ? o3 : expm1f(o3);
    o4 = o4 > 0.f ? o4 : expm1f(o4);
    o5 = o5 > 0.f ? o5 : expm1f(o5);
    o6 = o6 > 0.f ? o6 : expm1f(o6);
    o7 = o7 > 0.f ? o7 : expm1f(o7);
    uint4 ov;
    ov.x = (unsigned)f2bf(o0) | ((unsigned)f2bf(o1) << 16);
    ov.y = (unsigned)f2bf(o2) | ((unsigned)f2bf(o3) << 16);
    ov.z = (unsigned)f2bf(o4) | ((unsigned)f2bf(o5) << 16);
    ov.w = (unsigned)f2bf(o6) | ((unsigned)f2bf(o7) << 16);
    *(uint4*)(out + (size_t)v * 1024 + dd) = ov;
  }
}

// ---------------- sparse gat2 helpers ----------------
__global__ void k_rows2(const int* __restrict__ sid, const int* __restrict__ offs,
                        const int* __restrict__ csr, int* __restrict__ rowlist,
                        int* __restrict__ info) {
  __shared__ int degs[kB], starts[kB], total;
  int tid = threadIdx.x;
  int bv = tid >> 6, lane = tid & 63;
  if (tid < kB) {
    int v = sid[tid];
    degs[tid] = offs[v + 1] - offs[v];
  }
  __syncthreads();
  if (tid == 0) {
    int p = 0;
    for (int b = 0; b < kB; ++b) {
      starts[b] = p;
      int d = degs[b];
      if (p + d > kCap) d = kCap - p;
      degs[b] = d;
      p += d;
    }
    total = p;
  }
  __syncthreads();
  int v = sid[bv];
  int e0 = offs[v];
  int deg = degs[bv];
  int start = starts[bv];
  if (lane == 0) {
    info[bv] = start;
    info[4 + bv] = deg;
    info[8 + bv] = start;
  }
  __syncthreads();
  for (int idx = lane; idx < deg; idx += 64) {
    int s = csr[e0 + idx];
    rowlist[start + idx] = s;
    if (s == v) info[8 + bv] = start + idx;
  }
  for (int i = total + tid; i < kCap; i += 256) rowlist[i] = 0;
}

// ---------------- fused gat2 finish: el/er (phase A, LDS) + softmax-agg (phase B) ---------
__global__ __launch_bounds__(256) void k_gat2fin(const float* __restrict__ fc,
                                                 const float* __restrict__ al,
                                                 const float* __restrict__ ar,
                                                 const int* __restrict__ info,
                                                 const float* __restrict__ bias,
                                                 float* __restrict__ out) {
  __shared__ float el_s[kCap], er_s[kCap];
  int bv = blockIdx.x;
  int tid = threadIdx.x;
  int wid = tid >> 6, lane = tid & 63;
  int start = info[bv], cnt = info[4 + bv];
  int selfI = info[8 + bv] - start;

  // phase A: el/er for this graph's rows (one row per wave, strided)
  for (int i = wid; i < cnt; i += 4) {
    const float* row = fc + (size_t)(start + i) * 512 + lane * 8;
    float4 x0 = *(const float4*)(row);
    float4 x1 = *(const float4*)(row + 4);
    float4 a0 = *(const float4*)(al + lane * 8);
    float4 a1 = *(const float4*)(al + lane * 8 + 4);
    float4 r0 = *(const float4*)(ar + lane * 8);
    float4 r1 = *(const float4*)(ar + lane * 8 + 4);
    float a = x0.x * a0.x + x0.y * a0.y + x0.z * a0.z + x0.w * a0.w
            + x1.x * a1.x + x1.y * a1.y + x1.z * a1.z + x1.w * a1.w;
    float b = x0.x * r0.x + x0.y * r0.y + x0.z * r0.z + x0.w * r0.w
            + x1.x * r1.x + x1.y * r1.y + x1.z * r1.z + x1.w * r1.w;
#pragma unroll
    for (int o = 32; o; o >>= 1) {
      a += __shfl_xor(a, o);
      b += __shfl_xor(b, o);
    }
    if (lane == 0) { el_s[i] = a; er_s[i] = b; }
  }
  __syncthreads();

  // phase B: softmax over rows + weighted aggregation (original fin2 logic on LDS)
  float erv = er_s[selfI];
  float m = -1e30f;
  for (int i = 0; i < cnt; ++i) {
    float x = el_s[i] + erv;
    x = x > 0.f ? x : 0.2f * x;
    m = fmaxf(m, x);
  }
  float z = 0.f, s0 = 0.f, s1 = 0.f;
  for (int i = 0; i < cnt; ++i) {
    float x = el_s[i] + erv;
    x = x > 0.f ? x : 0.2f * x;
    float w = expf(x - m);
    z += w;
    s0 += w * fc[(size_t)(start + i) * 512 + tid];
    s1 += w * fc[(size_t)(start + i) * 512 + 256 + tid];
  }
  out[bv * 512 + tid] = s0 / z + bias[tid];
  out[bv * 512 + 256 + tid] = s1 / z + bias[256 + tid];
}

// ---------------- launcher ----------------
extern "C" void kernel_launch(void* const* d_in, const int* in_sizes, int n_in,
                              void* d_out, int out_size, void* d_ws, size_t ws_size,
                              hipStream_t stream) {
  const int*   all_words   = (const int*)d_in[0];
  const float* image_feats = (const float*)d_in[1];
  const int*   sentences   = (const int*)d_in[2];
  const float* sent_mask   = (const float*)d_in[3];
  const int*   utterances  = (const int*)d_in[4];
  const float* utt_mask    = (const float*)d_in[5];
  const int*   session_ids = (const int*)d_in[6];
  const int*   edge_src    = (const int*)d_in[7];
  const int*   edge_dst    = (const int*)d_in[8];
  const float* word_embed  = (const float*)d_in[9];
  const float* text_fc_w   = (const float*)d_in[10];
  const float* text_fc_b   = (const float*)d_in[11];
  const float* image_fc_w  = (const float*)d_in[12];
  const float* image_fc_b  = (const float*)d_in[13];
  const float* gat0_fc     = (const float*)d_in[14];
  const float* gat0_al     = (const float*)d_in[15];
  const float* gat0_ar     = (const float*)d_in[16];
  const float* gat0_b      = (const float*)d_in[17];
  const float* gat1_fc     = (const float*)d_in[18];
  const float* gat1_al     = (const float*)d_in[19];
  const float* gat1_ar     = (const float*)d_in[20];
  const float* gat1_b      = (const float*)d_in[21];
  const float* gat2_fc     = (const float*)d_in[22];
  const float* gat2_al     = (const float*)d_in[23];
  const float* gat2_ar     = (const float*)d_in[24];
  const float* gat2_b      = (const float*)d_in[25];

  const int E = in_sizes[7];

  char* base = (char*)d_ws;
  size_t off = 0;
  auto alloc = [&](size_t elems, size_t esz) -> void* {
    void* p = base + off;
    off += ((elems * esz + 255) / 256) * 256;
    return p;
  };
  unsigned short* Abf   = (unsigned short*)alloc((size_t)kN * kHid, 2);
  unsigned short* fbf   = (unsigned short*)alloc((size_t)kN * kHid, 2);
  unsigned short* txtbf = (unsigned short*)alloc((size_t)kTxtRows * kEmbPad, 2);
  unsigned short* imgbf = (unsigned short*)alloc((size_t)kB * kI * 2048, 2);
  unsigned short* wtTx  = (unsigned short*)alloc((size_t)kHid * kEmbPad, 2);
  unsigned short* wtIm  = (unsigned short*)alloc((size_t)kHid * 2048, 2);
  unsigned short* wtG0  = (unsigned short*)alloc((size_t)kNcB * kHid, 2);   // extended
  unsigned short* wtG1  = (unsigned short*)alloc((size_t)kNcB * kHid, 2);   // extended
  unsigned short* wtG2  = (unsigned short*)alloc((size_t)kOut * kHid, 2);
  float* Cimg   = (float*)alloc((size_t)kB * kI * kHid, 4);
  float* Cg2    = (float*)alloc((size_t)kCap * kOut, 4);
  float* sentb  = (float*)alloc((size_t)kB * kS * kEmb, 4);
  float* uttb   = (float*)alloc((size_t)kB * kU * kEmb, 4);
  float* sessb  = (float*)alloc((size_t)kB * kEmb, 4);
  float* el     = (float*)alloc((size_t)kN * 4, 4);
  float* er     = (float*)alloc((size_t)kN * 4, 4);
  float* wcsr   = (float*)alloc((size_t)E * 4, 4);
  int*   offs   = (int*)alloc(kN + 1, 4);
  int*   cnt    = (int*)alloc(kN, 4);
  int*   csr    = (int*)alloc(E, 4);
  int*   rmt    = (int*)alloc(kTxtRows, 4);
  int*   rmi    = (int*)alloc(kB * kI, 4);
  int*   rowl   = (int*)alloc(kCap, 4);
  int*   info   = (int*)alloc(16, 4);
  (void)ws_size; (void)n_in; (void)out_size;

  // 1) mega prep: transposes, img cvt, sent, rowmap, zeroing (NO wal/war here)
  constexpr int kPrepBlocks = 320 + 2048 + 1024 + 1024 + 512 + 512 + 256 + 34 + 34 + 256 + 128 + 60;
  k_prep0<<<kPrepBlocks, 256, 0, stream>>>(
      text_fc_w, wtTx, image_fc_w, wtIm, gat0_fc, wtG0, gat1_fc, wtG1, gat2_fc, wtG2,
      image_feats, imgbf, sentences, sent_mask, word_embed, sentb, rmt, rmi,
      cnt, Cimg, Cg2);

  // 2) utt + sess + wal/war (parallel)
  k_utt_sess<<<kB * kU + kB + 256, 256, 0, stream>>>(
      utterances, utt_mask, sentb, uttb, sessb,
      gat0_fc, gat1_fc, gat0_al, gat0_ar, gat1_al, gat1_ar, wtG0, wtG1);

  // 3) txt gather + edge count
  k_txtcount<<<kTxtRows + (E + 255) / 256, 256, 0, stream>>>(
      all_words, word_embed, sentb, uttb, sessb, txtbf, edge_dst, cnt, E);

  // 4) scan (also re-zeros cnt)   5) fill
  k_scan<<<1, 1024, 0, stream>>>(cnt, offs, kN);
  k_fill<<<(E + 255) / 256, 256, 0, stream>>>(edge_src, edge_dst, offs, cnt, csr, E);

  auto mmGrid = [](int M, int NcB_) {
    int nrt = (M + 127) / 128;
    return 8 * (NcB_ / 128) * ((nrt + 7) / 8);
  };

  // 6) text FC
  k_mm2<true, false><<<mmGrid(kTxtRows, kHid), 512, 0, stream>>>(
      txtbf, wtTx, text_fc_b, rmt, Abf, nullptr, nullptr, kTxtRows, kEmbPad, kHid, kHid);

  // 7-8) image FC via split-K
  k_mm_sk<<<dim3(kHid / 64, kB * kI / 64, 4), 256, 0, stream>>>(
      imgbf, wtIm, nullptr, Cimg, kB * kI, 2048, kHid, 512);
  k_sk_epi<<<(kB * kI * kHid + 255) / 256, 256, 0, stream>>>(
      Cimg, image_fc_b, rmi, Abf, kB * kI, kHid);

  // 9-10) GAT layer 0: GEMM -> softmax weights -> scalar-uniform aggregation
  k_mm2<true, true><<<mmGrid(kN, kNcB), 512, 0, stream>>>(
      Abf, wtG0, nullptr, nullptr, fbf, el, er, kN, kHid, kNcB, kHid);
  k_smaxw<<<kNB, 256, 0, stream>>>(el, er, offs, csr, wcsr, E);
  k_aggs<<<8 * kNBhi, 256, 0, stream>>>(fbf, offs, csr, wcsr, gat0_b, Abf, E);

  // 11-12) GAT layer 1
  k_mm2<true, true><<<mmGrid(kN, kNcB), 512, 0, stream>>>(
      Abf, wtG1, nullptr, nullptr, fbf, el, er, kN, kHid, kNcB, kHid);
  k_smaxw<<<kNB, 256, 0, stream>>>(el, er, offs, csr, wcsr, E);
  k_aggs<<<8 * kNBhi, 256, 0, stream>>>(fbf, offs, csr, wcsr, gat1_b, Abf, E);

  // 13-15) GAT layer 2, sparse (rows + GEMM + fused el/er+finish)
  k_rows2<<<1, 256, 0, stream>>>(session_ids, offs, csr, rowl, info);
  k_mm_sk<<<dim3(kOut / 64, kCap / 64, 4), 256, 0, stream>>>(
      Abf, wtG2, rowl, Cg2, kCap, kHid, kOut, 256);
  k_gat2fin<<<kB, 256, 0, stream>>>(Cg2, gat2_al, gat2_ar, info, gat2_b, (float*)d_out);
}

// Round 12
// 375.527 us; speedup vs baseline: 1.0398x; 1.0398x over previous
//
#include <hip/hip_runtime.h>
#include <math.h>

// ---------------- problem constants ----------------
constexpr int kB = 4, kW = 2000, kI = 64, kS = 64, kT = 24, kU = 32, kUS = 2;
constexpr int kPER = kW + kI + kS + kU + 1;   // 2161 nodes per graph
constexpr int kN   = kB * kPER;               // 8644 nodes total
constexpr int kTxtPer  = kW + kS + kU + 1;    // 2097 text rows per graph
constexpr int kTxtRows = kB * kTxtPer;        // 8388 text rows
constexpr int kEmb = 300;
constexpr int kEmbPad = 320;
constexpr int kHid = 1024;
constexpr int kOut = 512;
constexpr int kCap = 256;                     // max gathered rows for sparse gat2
constexpr int kMaxDeg = 256;                  // softmax LDS capacity per head
constexpr int kNcB = 1152;                    // gat B rows: 1024 f cols + 4 el + 4 er + 120 pad
constexpr int kNB  = kN / 4;                  // 2161 node-blocks (4 nodes each)
constexpr int kNBhi = (kNB + 1) / 2;          // 1081

typedef __attribute__((ext_vector_type(8))) short bf16x8;
typedef __attribute__((ext_vector_type(4))) float f32x4;
typedef __attribute__((ext_vector_type(2))) float f32x2;

__device__ __forceinline__ unsigned short f2bf(float f) {
  union { float f; unsigned int u; } x; x.f = f;
  unsigned int r = x.u + 0x7FFF + ((x.u >> 16) & 1);
  return (unsigned short)(r >> 16);
}
__device__ __forceinline__ float bf2f(unsigned short u) {
  union { unsigned int u; float f; } x; x.u = ((unsigned int)u) << 16;
  return x.f;
}
__device__ __forceinline__ float bflo(unsigned int u) {
  union { unsigned int u; float f; } x; x.u = u << 16; return x.f;
}
__device__ __forceinline__ float bfhi(unsigned int u) {
  union { unsigned int u; float f; } x; x.u = u & 0xFFFF0000u; return x.f;
}
// unpack 2 bf16 (one u32) -> float2 {lo, hi}; 2 VALU ops, feeds v_pk_fma_f32
__device__ __forceinline__ f32x2 bfpair(unsigned int u) {
  union { unsigned int ui[2]; f32x2 f; } x;
  x.ui[0] = u << 16;
  x.ui[1] = u & 0xFFFF0000u;
  return x.f;
}

// async global->LDS, 16B per lane. LDS dest is wave-uniform base + lane*16.
__device__ __forceinline__ void gl16(const unsigned short* g, unsigned short* l) {
  __builtin_amdgcn_global_load_lds(
      (const __attribute__((address_space(1))) void*)g,
      (__attribute__((address_space(3))) void*)l,
      16, 0, 0);
}

// ---------------- mega prep (round-11-proven structure, NO wal/war segment) ----------------
// segments: txW 320 | imW 2048 | g0 1024 | g1 1024 | g2 512 | imgcvt 512 |
//           sent 256 | rowmap 34 | zcnt 34 | zCimg 256 | zCg2 128 | zpad 60
__global__ __launch_bounds__(256) void k_prep0(
    const float* __restrict__ tx_w, unsigned short* __restrict__ o_tx,
    const float* __restrict__ im_w, unsigned short* __restrict__ o_im,
    const float* __restrict__ g0_w, unsigned short* __restrict__ o_g0,   // [kNcB][1024]
    const float* __restrict__ g1_w, unsigned short* __restrict__ o_g1,   // [kNcB][1024]
    const float* __restrict__ g2_w, unsigned short* __restrict__ o_g2,
    const float* __restrict__ img, unsigned short* __restrict__ o_img,
    const int* __restrict__ sents, const float* __restrict__ smask,
    const float* __restrict__ wemb, float* __restrict__ sent,
    int* __restrict__ rmt, int* __restrict__ rmi,
    int* __restrict__ cnt, float* __restrict__ Cimg, float* __restrict__ Cg2) {
  int b = blockIdx.x;
  int tid = threadIdx.x;
  int tx = tid & 31, ty = tid >> 5;

  const float* in = nullptr; unsigned short* out = nullptr; int K = 0, N = 0, Kpad = 0, nbx = 0;
  if (b < 320)                { in = tx_w; out = o_tx; K = kEmb; N = kHid; Kpad = kEmbPad; nbx = 32; }
  else if ((b -= 320) < 2048) { in = im_w; out = o_im; K = 2048; N = kHid; Kpad = 2048; nbx = 32; }
  else if ((b -= 2048) < 1024){ in = g0_w; out = o_g0; K = kHid; N = kHid; Kpad = kHid; nbx = 32; }
  else if ((b -= 1024) < 1024){ in = g1_w; out = o_g1; K = kHid; N = kHid; Kpad = kHid; nbx = 32; }
  else if ((b -= 1024) < 512) { in = g2_w; out = o_g2; K = kHid; N = kOut; Kpad = kHid; nbx = 16; }
  else if ((b -= 512) < 512) {
    int i = b * 1024 + tid * 4;
    float4 v = *(const float4*)(img + i);
    ushort4 o; o.x = f2bf(v.x); o.y = f2bf(v.y); o.z = f2bf(v.z); o.w = f2bf(v.w);
    *(ushort4*)(o_img + i) = o;
    return;
  } else if ((b -= 512) < 256) {
    // sentence masked mean
    __shared__ int idx[kT];
    __shared__ float mk[kT];
    __shared__ float s_cnt;
    if (tid < kT) { idx[tid] = sents[b * kT + tid]; mk[tid] = smask[b * kT + tid]; }
    __syncthreads();
    if (tid == 0) {
      float c = 0.f;
      for (int i = 0; i < kT; ++i) c += mk[i];
      s_cnt = (c == 0.f) ? 1.f : c;
    }
    __syncthreads();
    for (int d = tid; d < kEmb; d += 256) {
      float acc = 0.f;
      for (int i = 0; i < kT; ++i) acc += wemb[idx[i] * kEmb + d] * mk[i];
      sent[b * kEmb + d] = acc / s_cnt;
    }
    return;
  } else if ((b -= 256) < 34) {
    int i = b * 256 + tid;
    if (i < kTxtRows) {
      int g = i / kTxtPer, j = i - g * kTxtPer;
      int base = g * kPER;
      int node;
      if (j < kW)                 node = base + j;
      else if (j < kW + kS)       node = base + kW + kI + (j - kW);
      else if (j < kW + kS + kU)  node = base + kW + kI + kS + (j - kW - kS);
      else                        node = base + kW + kI + kS + kU;
      rmt[i] = node;
    }
    if (i < kB * kI) {
      int g = i >> 6;
      rmi[i] = g * kPER + kW + (i & 63);
    }
    return;
  } else if ((b -= 34) < 34) {
    int i = b * 256 + tid;
    if (i < kN) cnt[i] = 0;
    return;
  } else if ((b -= 34) < 256) {
    uint4 z = make_uint4(0u, 0u, 0u, 0u);
    ((uint4*)Cimg)[b * 256 + tid] = z;
    return;
  } else if ((b -= 256) < 128) {
    uint4 z = make_uint4(0u, 0u, 0u, 0u);
    ((uint4*)Cg2)[b * 256 + tid] = z;
    return;
  } else {
    // zero pad rows 1032..1151 of both extended gat weights (60 blocks)
    b -= 128;
    int i = b * 256 + tid;                 // 0..15359
    uint4 z = make_uint4(0u, 0u, 0u, 0u);
    ((uint4*)(o_g0 + (size_t)1032 * kHid))[i] = z;
    ((uint4*)(o_g1 + (size_t)1032 * kHid))[i] = z;
    return;
  }

  // transpose body (reached only for the 5 transpose segments)
  int bx = b % nbx, by = b / nbx;
  __shared__ float t[32][33];
  int n = bx * 32 + tx;
#pragma unroll
  for (int j = 0; j < 4; ++j) {
    int k = by * 32 + ty + j * 8;
    t[ty + j * 8][tx] = (k < K) ? in[(size_t)k * N + n] : 0.f;
  }
  __syncthreads();
#pragma unroll
  for (int j = 0; j < 4; ++j) {
    int nn = bx * 32 + ty + j * 8;
    int kk = by * 32 + tx;
    out[(size_t)nn * Kpad + kk] = f2bf(t[tx][ty + j * 8]);
  }
}

// ---------------- utt + sess + wal/war (parallel, off critical path) ----------------
// blocks: [0, kB*kU) utt | [kB*kU, kB*kU+kB) sess | [132, 132+256) wal/war
__global__ __launch_bounds__(256) void k_utt_sess(const int* __restrict__ utts,
                                                  const float* __restrict__ umask,
                                                  const float* __restrict__ sent,
                                                  float* __restrict__ utt,
                                                  float* __restrict__ sess,
                                                  const float* __restrict__ g0_w,
                                                  const float* __restrict__ g1_w,
                                                  const float* __restrict__ g0_al,
                                                  const float* __restrict__ g0_ar,
                                                  const float* __restrict__ g1_al,
                                                  const float* __restrict__ g1_ar,
                                                  unsigned short* __restrict__ o_g0,
                                                  unsigned short* __restrict__ o_g1) {
  int blk = blockIdx.x;
  int tid = threadIdx.x;
  if (blk < kB * kU) {
    int bu = blk, b = bu / kU;
    __shared__ int idx[kUS];
    __shared__ float mk[kUS];
    __shared__ float s_cnt;
    if (tid < kUS) { idx[tid] = utts[bu * kUS + tid]; mk[tid] = umask[bu * kUS + tid]; }
    __syncthreads();
    if (tid == 0) {
      float c = 0.f;
      for (int i = 0; i < kUS; ++i) c += mk[i];
      s_cnt = (c == 0.f) ? 1.f : c;
    }
    __syncthreads();
    for (int d = tid; d < kEmb; d += 256) {
      float acc = 0.f;
      for (int i = 0; i < kUS; ++i) acc += sent[(b * kS + idx[i]) * kEmb + d] * mk[i];
      utt[bu * kEmb + d] = acc / s_cnt;
    }
  } else if (blk < kB * kU + kB) {
    int b = blk - kB * kU;                // graph index
    for (int d = tid; d < kEmb; d += 256) {
      float acc = 0.f;
      for (int u = 0; u < kU; ++u) {
        float ua = 0.f, c = 0.f;
        for (int us = 0; us < kUS; ++us) {
          int i = (b * kU + u) * kUS + us;
          int sidx = utts[i];
          float m = umask[i];
          ua += sent[(b * kS + sidx) * kEmb + d] * m;
          c += m;
        }
        if (c == 0.f) c = 1.f;
        acc += ua / c;
      }
      sess[b * kEmb + d] = acc * (1.f / kU);
    }
  } else {
    // wal/war projections: 256 blocks, each handles 64 k's of one (layer,which,head,kblk).
    // wt[1024 + which*4 + h][k] = sum_d fc[k][h*256+d] * a[h*256+d]
    int b = blk - (kB * kU + kB);         // 0..255
    int layer = b >> 7, rem = b & 127;
    int which = rem >> 6;
    int rem2 = rem & 63;
    int h = rem2 >> 4, kblk = rem2 & 15;
    const float* fc = layer ? g1_w : g0_w;
    const float* a  = layer ? (which ? g1_ar : g1_al) : (which ? g0_ar : g0_al);
    unsigned short* wt = layer ? o_g1 : o_g0;
    int kl = tid >> 2, q = tid & 3;       // 64 k's per block, 4 threads per k
    int k = kblk * 64 + kl;
    float s = 0.f;
    const float* fr = fc + (size_t)k * kHid + h * 256 + q * 64;
    const float* av = a + h * 256 + q * 64;
    for (int d = 0; d < 64; ++d) s += fr[d] * av[d];
    s += __shfl_xor(s, 1);
    s += __shfl_xor(s, 2);
    if (q == 0) wt[(size_t)(1024 + which * 4 + h) * kHid + k] = f2bf(s);
  }
}

// ---------------- txt gather (bf16) + edge count fused ----------------
__global__ __launch_bounds__(256) void k_txtcount(const int* __restrict__ aw,
                                                  const float* __restrict__ wemb,
                                                  const float* __restrict__ sent,
                                                  const float* __restrict__ utt,
                                                  const float* __restrict__ sess,
                                                  unsigned short* __restrict__ txt,
                                                  const int* __restrict__ dst,
                                                  int* __restrict__ cnt, int E) {
  int blk = blockIdx.x;
  int tid = threadIdx.x;
  if (blk < kTxtRows) {
    int r = blk;
    int g = r / kTxtPer, j = r - g * kTxtPer;
    const float* src;
    if (j < kW)                 src = wemb + (size_t)aw[g * kW + j] * kEmb;
    else if (j < kW + kS)       src = sent + (size_t)(g * kS + (j - kW)) * kEmb;
    else if (j < kW + kS + kU)  src = utt  + (size_t)(g * kU + (j - kW - kS)) * kEmb;
    else                        src = sess + (size_t)g * kEmb;
    for (int d = tid; d < kEmbPad; d += 256)
      txt[(size_t)r * kEmbPad + d] = (d < kEmb) ? f2bf(src[d]) : (unsigned short)0;
  } else {
    int e = (blk - kTxtRows) * 256 + tid;
    if (e < E) atomicAdd(&cnt[dst[e]], 1);
  }
}

// ---------------- bf16 MFMA GEMM, XCD-banded 1-D grid, optional el/er cols ----------------
// staging via global_load_lds (linear LDS dest, inverse-swizzled global source).
// r6 structure: 128x128 tile, 32KB LDS, single buffer, 512 threads = 8 waves/block
// (4M x 2N wave grid, 32x64 per wave) -> ~20 waves/CU to hide the barrier drain.
template <bool OBF, bool ELR>
__global__ __launch_bounds__(512) void k_mm2(const unsigned short* __restrict__ A,
                                             const unsigned short* __restrict__ Bt,
                                             const float* __restrict__ bias,
                                             const int* __restrict__ rmap,
                                             void* __restrict__ Cout,
                                             float* __restrict__ el,
                                             float* __restrict__ er,
                                             int M, int K, int NcB, int NcOut) {
  __shared__ __align__(16) unsigned short As[128 * 64];
  __shared__ __align__(16) unsigned short Bs[128 * 64];
  int nCol = NcB >> 7;
  int bi = blockIdx.x;
  int xcd = bi & 7, bj = bi >> 3;
  int colTile = bj % nCol;
  int rowTile = ((bj / nCol) << 3) + xcd;
  int row0 = rowTile << 7;
  if (row0 >= M) return;
  int col0 = colTile << 7;

  int tid = threadIdx.x;
  int wid = tid >> 6, lane = tid & 63, quad = lane >> 4, l16 = lane & 15;
  int wm = wid >> 1, wn = wid & 1;      // wave tile: 32M x 64N

  f32x4 acc[2][4];
  f32x4 zero4 = {0.f, 0.f, 0.f, 0.f};
#pragma unroll
  for (int i = 0; i < 2; ++i)
#pragma unroll
    for (int j = 0; j < 4; ++j) acc[i][j] = zero4;

  // lane -> (row-in-8, fetched chunk). LDS packet: wave writes 8 rows x 128B linearly;
  // lane l covers row (l>>3), byte-chunk (l&7). Source chunk = (l&7) ^ (l>>3) so that
  // LDS position c of row r holds global chunk c ^ (r&7)  (matches read-side swizzle).
  int lr = lane >> 3;
  int swc = (lane & 7) ^ lr;

  for (int k0 = 0; k0 < K; k0 += 64) {
    __syncthreads();
#pragma unroll
    for (int i = 0; i < 2; ++i) {       // 16 A-packets + 16 B-packets over 8 waves
      int rb = i * 64 + wid * 8;        // 8-row packet base (wave-uniform)
      int r = rb + lr;
      int grow = row0 + r;
      if (grow >= M) grow = row0;       // clamp: rows discarded in epilogue
      gl16(A + (size_t)grow * K + k0 + (swc << 3), &As[rb * 64]);
      int nrow = col0 + r;
      gl16(Bt + (size_t)nrow * K + k0 + (swc << 3), &Bs[rb * 64]);
    }
    __syncthreads();                    // drains vmcnt before barrier
#pragma unroll
    for (int s = 0; s < 2; ++s) {
      int cc = s * 4 + quad;
      bf16x8 aF[2], bF[4];
#pragma unroll
      for (int mi = 0; mi < 2; ++mi) {
        int r = wm * 32 + mi * 16 + l16;
        aF[mi] = *(const bf16x8*)&As[r * 64 + ((cc ^ (r & 7)) << 3)];
      }
#pragma unroll
      for (int ni = 0; ni < 4; ++ni) {
        int r = wn * 64 + ni * 16 + l16;
        bF[ni] = *(const bf16x8*)&Bs[r * 64 + ((cc ^ (r & 7)) << 3)];
      }
#pragma unroll
      for (int mi = 0; mi < 2; ++mi)
#pragma unroll
        for (int ni = 0; ni < 4; ++ni)
          acc[mi][ni] = __builtin_amdgcn_mfma_f32_16x16x32_bf16(aF[mi], bF[ni], acc[mi][ni], 0, 0, 0);
    }
  }

  // ---- epilogue (C/D layout: col=lane&15, row=quad*4+reg) ----
#pragma unroll
  for (int mi = 0; mi < 2; ++mi) {
#pragma unroll
    for (int ni = 0; ni < 4; ++ni) {
      int gm0 = row0 + wm * 32 + mi * 16 + quad * 4;
      int gn  = col0 + wn * 64 + ni * 16 + l16;
      float bv = (bias && gn < NcOut) ? bias[gn] : 0.f;
#pragma unroll
      for (int i = 0; i < 4; ++i) {
        int r = gm0 + i;
        if (r >= M) continue;
        float v = acc[mi][ni][i] + bv;
        if (gn < NcOut) {
          if (OBF) {
            int orow = rmap ? rmap[r] : r;
            ((unsigned short*)Cout)[(size_t)orow * NcOut + gn] = f2bf(v);
          } else {
            ((float*)Cout)[(size_t)r * NcOut + gn] = v;
          }
        } else if (ELR) {
          int gn2 = gn - NcOut;
          if (gn2 < 4)      el[r * 4 + gn2] = v;
          else if (gn2 < 8) er[r * 4 + gn2 - 4] = v;
        }
      }
    }
  }
}

// ---------------- split-K bf16 MFMA GEMM (64x64 tile, optional A-row gather) ----------------
__global__ __launch_bounds__(256) void k_mm_sk(const unsigned short* __restrict__ A,
                                               const unsigned short* __restrict__ Bt,
                                               const int* __restrict__ rowlist,
                                               float* __restrict__ C,
                                               int M, int K, int Nc, int Kc) {
  __shared__ __align__(16) unsigned short As[64 * 64];
  __shared__ __align__(16) unsigned short Bs[64 * 64];
  int tid = threadIdx.x;
  int wid = tid >> 6, lane = tid & 63, quad = lane >> 4, l16 = lane & 15;
  int row0 = blockIdx.y * 64, col0 = blockIdx.x * 64;
  int k0 = blockIdx.z * Kc;
  int k1 = k0 + Kc; if (k1 > K) k1 = K;

  f32x4 acc[4];
  f32x4 zero4 = {0.f, 0.f, 0.f, 0.f};
#pragma unroll
  for (int i = 0; i < 4; ++i) acc[i] = zero4;

  int lr = lane >> 3;
  int swc = (lane & 7) ^ lr;

  // hoist A row indices (gather) out of the K loop
  int arow[2];
#pragma unroll
  for (int i = 0; i < 2; ++i) {
    int grow = row0 + i * 32 + wid * 8 + lr;
    int ar = 0;
    if (grow < M) ar = rowlist ? rowlist[grow] : grow;
    arow[i] = ar;
  }

  for (int kk = k0; kk < k1; kk += 64) {
    __syncthreads();
#pragma unroll
    for (int i = 0; i < 2; ++i) {
      int rb = i * 32 + wid * 8;
      gl16(A + (size_t)arow[i] * K + kk + (swc << 3), &As[rb * 64]);
      int nrow = col0 + rb + lr;
      gl16(Bt + (size_t)nrow * K + kk + (swc << 3), &Bs[rb * 64]);
    }
    __syncthreads();
#pragma unroll
    for (int s = 0; s < 2; ++s) {
      int cc = s * 4 + quad;
      bf16x8 bF;
      {
        int r = wid * 16 + l16;
        bF = *(const bf16x8*)&Bs[r * 64 + ((cc ^ (r & 7)) << 3)];
      }
#pragma unroll
      for (int mi = 0; mi < 4; ++mi) {
        int r = mi * 16 + l16;
        bf16x8 aF = *(const bf16x8*)&As[r * 64 + ((cc ^ (r & 7)) << 3)];
        acc[mi] = __builtin_amdgcn_mfma_f32_16x16x32_bf16(aF, bF, acc[mi], 0, 0, 0);
      }
    }
  }
#pragma unroll
  for (int mi = 0; mi < 4; ++mi) {
#pragma unroll
    for (int i = 0; i < 4; ++i) {
      int r = row0 + mi * 16 + quad * 4 + i;
      int c = col0 + wid * 16 + l16;
      if (r < M) atomicAdd(&C[(size_t)r * Nc + c], acc[mi][i]);
    }
  }
}

__global__ void k_sk_epi(const float* __restrict__ Cw, const float* __restrict__ bias,
                         const int* __restrict__ rmap, unsigned short* __restrict__ out,
                         int M, int Nc) {
  int i = blockIdx.x * blockDim.x + threadIdx.x;
  if (i >= M * Nc) return;
  int r = i / Nc, c = i - r * Nc;
  out[(size_t)rmap[r] * Nc + c] = f2bf(Cw[i] + bias[c]);
}

// ---------------- CSR build ----------------
__global__ void k_scan(int* __restrict__ deg, int* __restrict__ offs, int n) {
  __shared__ int part[1024];
  int tid = threadIdx.x;
  int per = (n + 1023) >> 10;
  int start = tid * per;
  int local = 0;
  for (int i = 0; i < per; ++i) { int idx = start + i; if (idx < n) local += deg[idx]; }
  part[tid] = local;
  __syncthreads();
  for (int off = 1; off < 1024; off <<= 1) {
    int add = (tid >= off) ? part[tid - off] : 0;
    __syncthreads();
    part[tid] += add;
    __syncthreads();
  }
  int run = (tid == 0) ? 0 : part[tid - 1];
  for (int i = 0; i < per; ++i) {
    int idx = start + i;
    if (idx < n) { offs[idx] = run; run += deg[idx]; }
  }
  if (tid == 1023) offs[n] = part[1023];
  __syncthreads();
  for (int i = tid; i < n; i += 1024) deg[i] = 0;
}

__global__ void k_fill(const int* __restrict__ src, const int* __restrict__ dst,
                       const int* __restrict__ offs, int* __restrict__ cur,
                       int* __restrict__ csr, int E) {
  int e = blockIdx.x * blockDim.x + threadIdx.x;
  if (e < E) {
    int d = dst[e];
    int slot = offs[d] + atomicAdd(&cur[d], 1);
    csr[slot] = src[e];
  }
}

// ---------------- head-sliced softmax + aggregation (one head per block, XCD-pinned) ------
// grid = 8 * kNBhi. bid&7 -> XCD; head g = xcd&3 so each XCD's L2 holds one 4.4MB head
// slice of f. Block = 4 waves, wave w handles node nb*4+w for head g.
// r8 config: register softmax (deg<=64), packed (w,s) in one LDS uint2, f32x2 packed FMA.
__global__ __launch_bounds__(256) void k_agg3h(const unsigned short* __restrict__ f,
                                               const float* __restrict__ el,
                                               const float* __restrict__ er,
                                               const int* __restrict__ offs,
                                               const int* __restrict__ csr,
                                               const float* __restrict__ bias,
                                               unsigned short* __restrict__ out) {
  __shared__ uint2 ws[4][kMaxDeg];        // .x = f32 bits of weight, .y = src node
  int bid = blockIdx.x;
  int xcd = bid & 7;
  int g = xcd & 3;                        // head for this block (L2-pinned per XCD pair)
  int nb = (xcd >> 2) * kNBhi + (bid >> 3);
  if (nb >= kNB) return;
  int tid = threadIdx.x;
  int wid = tid >> 6, lane = tid & 63;
  int v = nb * 4 + wid;                   // kN == kNB*4 exactly

  int e0 = offs[v];
  int deg = offs[v + 1] - e0;
  if (deg > kMaxDeg) deg = kMaxDeg;

  float erv = er[v * 4 + g];

  if (deg <= 64) {
    // ---- single-pass register softmax (common case: avg deg ~17) ----
    int s = 0;
    float x = -1e30f;
    if (lane < deg) {
      s = csr[e0 + lane];
      x = el[s * 4 + g] + erv;
      x = x > 0.f ? x : 0.2f * x;
    }
    float m = x;
#pragma unroll
    for (int o = 32; o; o >>= 1) m = fmaxf(m, __shfl_xor(m, o));
    float w = expf(x - m);                // inactive lanes: exp(-huge) = 0
    float zs = w;
#pragma unroll
    for (int o = 32; o; o >>= 1) zs += __shfl_xor(zs, o);
    w *= 1.f / zs;
    ws[wid][lane] = make_uint2(__float_as_uint(w), (unsigned)s);
  } else {
    // ---- generic 3-pass path (deg > 64, rare) ----
    float m = -1e30f;
    for (int base = 0; base < deg; base += 64) {
      int idx = base + lane;
      float x = -1e30f;
      if (idx < deg) {
        int s = csr[e0 + idx];
        x = el[s * 4 + g] + erv;
        x = x > 0.f ? x : 0.2f * x;
        ws[wid][idx] = make_uint2(__float_as_uint(x), (unsigned)s);
      }
      float mm = x;
#pragma unroll
      for (int o = 32; o; o >>= 1) mm = fmaxf(mm, __shfl_xor(mm, o));
      m = fmaxf(m, mm);
    }
    float zs = 0.f;
    for (int base = 0; base < deg; base += 64) {
      int idx = base + lane;
      if (idx < deg) {
        float w = expf(__uint_as_float(ws[wid][idx].x) - m);
        ws[wid][idx].x = __float_as_uint(w);
        zs += w;
      }
    }
#pragma unroll
    for (int o = 32; o; o >>= 1) zs += __shfl_xor(zs, o);
    float rz = 1.f / zs;
    for (int base = 0; base < deg; base += 64) {
      int idx = base + lane;
      if (idx < deg)
        ws[wid][idx].x = __float_as_uint(__uint_as_float(ws[wid][idx].x) * rz);
    }
  }

  // ---- aggregation: 256 dims of head g, 8 edges/iter (4 per half-wave), packed f32 ----
  int side = lane >> 5, l32 = lane & 31;
  const char* fb = (const char*)f + (size_t)(g * 256 + l32 * 8) * 2;
  f32x2 a01 = {0.f, 0.f}, a23 = {0.f, 0.f}, a45 = {0.f, 0.f}, a67 = {0.f, 0.f};
  f32x2 c01 = {0.f, 0.f}, c23 = {0.f, 0.f}, c45 = {0.f, 0.f}, c67 = {0.f, 0.f};
  int e = 0;
  for (; e + 8 <= deg; e += 8) {
    int i0 = e + side, i1 = e + 2 + side, i2 = e + 4 + side, i3 = e + 6 + side;
    uint2 t0 = ws[wid][i0]; uint2 t1 = ws[wid][i1];
    uint2 t2 = ws[wid][i2]; uint2 t3 = ws[wid][i3];
    uint4 f0 = *(const uint4*)(fb + ((size_t)t0.y << 11));
    uint4 f1 = *(const uint4*)(fb + ((size_t)t1.y << 11));
    uint4 f2 = *(const uint4*)(fb + ((size_t)t2.y << 11));
    uint4 f3 = *(const uint4*)(fb + ((size_t)t3.y << 11));
    float w0 = __uint_as_float(t0.x), w1 = __uint_as_float(t1.x);
    float w2 = __uint_as_float(t2.x), w3 = __uint_as_float(t3.x);
    f32x2 wv0 = {w0, w0}, wv1 = {w1, w1}, wv2 = {w2, w2}, wv3 = {w3, w3};
    a01 += wv0 * bfpair(f0.x); a23 += wv0 * bfpair(f0.y);
    a45 += wv0 * bfpair(f0.z); a67 += wv0 * bfpair(f0.w);
    c01 += wv1 * bfpair(f1.x); c23 += wv1 * bfpair(f1.y);
    c45 += wv1 * bfpair(f1.z); c67 += wv1 * bfpair(f1.w);
    a01 += wv2 * bfpair(f2.x); a23 += wv2 * bfpair(f2.y);
    a45 += wv2 * bfpair(f2.z); a67 += wv2 * bfpair(f2.w);
    c01 += wv3 * bfpair(f3.x); c23 += wv3 * bfpair(f3.y);
    c45 += wv3 * bfpair(f3.z); c67 += wv3 * bfpair(f3.w);
  }
  for (; e < deg; e += 2) {
    int idx = e + side;
    if (idx < deg) {
      uint2 t = ws[wid][idx];
      uint4 fv = *(const uint4*)(fb + ((size_t)t.y << 11));
      float w = __uint_as_float(t.x);
      f32x2 wv = {w, w};
      a01 += wv * bfpair(fv.x); a23 += wv * bfpair(fv.y);
      a45 += wv * bfpair(fv.z); a67 += wv * bfpair(fv.w);
    }
  }
  a01 += c01; a23 += c23; a45 += c45; a67 += c67;
  float a0 = a01.x, a1 = a01.y, a2 = a23.x, a3 = a23.y;
  float a4 = a45.x, a5 = a45.y, a6 = a67.x, a7 = a67.y;
  a0 += __shfl_xor(a0, 32); a1 += __shfl_xor(a1, 32);
  a2 += __shfl_xor(a2, 32); a3 += __shfl_xor(a3, 32);
  a4 += __shfl_xor(a4, 32); a5 += __shfl_xor(a5, 32);
  a6 += __shfl_xor(a6, 32); a7 += __shfl_xor(a7, 32);

  if (side == 0) {
    int d0 = g * 256 + l32 * 8;
    float4 b0 = *(const float4*)(bias + d0);
    float4 b1 = *(const float4*)(bias + d0 + 4);
    float o0 = a0 + b0.x, o1 = a1 + b0.y, o2 = a2 + b0.z, o3 = a3 + b0.w;
    float o4 = a4 + b1.x, o5 = a5 + b1.y, o6 = a6 + b1.z, o7 = a7 + b1.w;
    o0 = o0 > 0.f ? o0 : expm1f(o0);
    o1 = o1 > 0.f ? o1 : expm1f(o1);
    o2 = o2 > 0.f ? o2 : expm1f(o2);
    o3 = o3 > 0.f ? o3 : expm1f(o3);
    o4 = o4 > 0.f ? o4 : expm1f(o4);
    o5 = o5 > 0.f ? o5 : expm1f(o5);
    o6 = o6 > 0.f ? o6 : expm1f(o6);
    o7 = o7 > 0.f ? o7 : expm1f(o7);
    uint4 ov;
    ov.x = (unsigned)f2bf(o0) | ((unsigned)f2bf(o1) << 16);
    ov.y = (unsigned)f2bf(o2) | ((unsigned)f2bf(o3) << 16);
    ov.z = (unsigned)f2bf(o4) | ((unsigned)f2bf(o5) << 16);
    ov.w = (unsigned)f2bf(o6) | ((unsigned)f2bf(o7) << 16);
    *(uint4*)(out + (size_t)v * 1024 + d0) = ov;
  }
}

// ---------------- sparse gat2 helpers ----------------
__global__ void k_rows2(const int* __restrict__ sid, const int* __restrict__ offs,
                        const int* __restrict__ csr, int* __restrict__ rowlist,
                        int* __restrict__ info) {
  __shared__ int degs[kB], starts[kB], total;
  int tid = threadIdx.x;
  int bv = tid >> 6, lane = tid & 63;
  if (tid < kB) {
    int v = sid[tid];
    degs[tid] = offs[v + 1] - offs[v];
  }
  __syncthreads();
  if (tid == 0) {
    int p = 0;
    for (int b = 0; b < kB; ++b) {
      starts[b] = p;
      int d = degs[b];
      if (p + d > kCap) d = kCap - p;
      degs[b] = d;
      p += d;
    }
    total = p;
  }
  __syncthreads();
  int v = sid[bv];
  int e0 = offs[v];
  int deg = degs[bv];
  int start = starts[bv];
  if (lane == 0) {
    info[bv] = start;
    info[4 + bv] = deg;
    info[8 + bv] = start;
  }
  __syncthreads();
  for (int idx = lane; idx < deg; idx += 64) {
    int s = csr[e0 + idx];
    rowlist[start + idx] = s;
    if (s == v) info[8 + bv] = start + idx;
  }
  for (int i = total + tid; i < kCap; i += 256) rowlist[i] = 0;
}

// ---------------- fused gat2 finish: el/er (phase A, LDS) + softmax-agg (phase B) ---------
__global__ __launch_bounds__(256) void k_gat2fin(const float* __restrict__ fc,
                                                 const float* __restrict__ al,
                                                 const float* __restrict__ ar,
                                                 const int* __restrict__ info,
                                                 const float* __restrict__ bias,
                                                 float* __restrict__ out) {
  __shared__ float el_s[kCap], er_s[kCap];
  int bv = blockIdx.x;
  int tid = threadIdx.x;
  int wid = tid >> 6, lane = tid & 63;
  int start = info[bv], cnt = info[4 + bv];
  int selfI = info[8 + bv] - start;

  // phase A: el/er for this graph's rows (one row per wave, strided)
  for (int i = wid; i < cnt; i += 4) {
    const float* row = fc + (size_t)(start + i) * 512 + lane * 8;
    float4 x0 = *(const float4*)(row);
    float4 x1 = *(const float4*)(row + 4);
    float4 a0 = *(const float4*)(al + lane * 8);
    float4 a1 = *(const float4*)(al + lane * 8 + 4);
    float4 r0 = *(const float4*)(ar + lane * 8);
    float4 r1 = *(const float4*)(ar + lane * 8 + 4);
    float a = x0.x * a0.x + x0.y * a0.y + x0.z * a0.z + x0.w * a0.w
            + x1.x * a1.x + x1.y * a1.y + x1.z * a1.z + x1.w * a1.w;
    float b = x0.x * r0.x + x0.y * r0.y + x0.z * r0.z + x0.w * r0.w
            + x1.x * r1.x + x1.y * r1.y + x1.z * r1.z + x1.w * r1.w;
#pragma unroll
    for (int o = 32; o; o >>= 1) {
      a += __shfl_xor(a, o);
      b += __shfl_xor(b, o);
    }
    if (lane == 0) { el_s[i] = a; er_s[i] = b; }
  }
  __syncthreads();

  // phase B: softmax over rows + weighted aggregation (original fin2 logic on LDS)
  float erv = er_s[selfI];
  float m = -1e30f;
  for (int i = 0; i < cnt; ++i) {
    float x = el_s[i] + erv;
    x = x > 0.f ? x : 0.2f * x;
    m = fmaxf(m, x);
  }
  float z = 0.f, s0 = 0.f, s1 = 0.f;
  for (int i = 0; i < cnt; ++i) {
    float x = el_s[i] + erv;
    x = x > 0.f ? x : 0.2f * x;
    float w = expf(x - m);
    z += w;
    s0 += w * fc[(size_t)(start + i) * 512 + tid];
    s1 += w * fc[(size_t)(start + i) * 512 + 256 + tid];
  }
  out[bv * 512 + tid] = s0 / z + bias[tid];
  out[bv * 512 + 256 + tid] = s1 / z + bias[256 + tid];
}

// ---------------- launcher ----------------
extern "C" void kernel_launch(void* const* d_in, const int* in_sizes, int n_in,
                              void* d_out, int out_size, void* d_ws, size_t ws_size,
                              hipStream_t stream) {
  const int*   all_words   = (const int*)d_in[0];
  const float* image_feats = (const float*)d_in[1];
  const int*   sentences   = (const int*)d_in[2];
  const float* sent_mask   = (const float*)d_in[3];
  const int*   utterances  = (const int*)d_in[4];
  const float* utt_mask    = (const float*)d_in[5];
  const int*   session_ids = (const int*)d_in[6];
  const int*   edge_src    = (const int*)d_in[7];
  const int*   edge_dst    = (const int*)d_in[8];
  const float* word_embed  = (const float*)d_in[9];
  const float* text_fc_w   = (const float*)d_in[10];
  const float* text_fc_b   = (const float*)d_in[11];
  const float* image_fc_w  = (const float*)d_in[12];
  const float* image_fc_b  = (const float*)d_in[13];
  const float* gat0_fc     = (const float*)d_in[14];
  const float* gat0_al     = (const float*)d_in[15];
  const float* gat0_ar     = (const float*)d_in[16];
  const float* gat0_b      = (const float*)d_in[17];
  const float* gat1_fc     = (const float*)d_in[18];
  const float* gat1_al     = (const float*)d_in[19];
  const float* gat1_ar     = (const float*)d_in[20];
  const float* gat1_b      = (const float*)d_in[21];
  const float* gat2_fc     = (const float*)d_in[22];
  const float* gat2_al     = (const float*)d_in[23];
  const float* gat2_ar     = (const float*)d_in[24];
  const float* gat2_b      = (const float*)d_in[25];

  const int E = in_sizes[7];

  char* base = (char*)d_ws;
  size_t off = 0;
  auto alloc = [&](size_t elems, size_t esz) -> void* {
    void* p = base + off;
    off += ((elems * esz + 255) / 256) * 256;
    return p;
  };
  unsigned short* Abf   = (unsigned short*)alloc((size_t)kN * kHid, 2);
  unsigned short* fbf   = (unsigned short*)alloc((size_t)kN * kHid, 2);
  unsigned short* txtbf = (unsigned short*)alloc((size_t)kTxtRows * kEmbPad, 2);
  unsigned short* imgbf = (unsigned short*)alloc((size_t)kB * kI * 2048, 2);
  unsigned short* wtTx  = (unsigned short*)alloc((size_t)kHid * kEmbPad, 2);
  unsigned short* wtIm  = (unsigned short*)alloc((size_t)kHid * 2048, 2);
  unsigned short* wtG0  = (unsigned short*)alloc((size_t)kNcB * kHid, 2);   // extended
  unsigned short* wtG1  = (unsigned short*)alloc((size_t)kNcB * kHid, 2);   // extended
  unsigned short* wtG2  = (unsigned short*)alloc((size_t)kOut * kHid, 2);
  float* Cimg   = (float*)alloc((size_t)kB * kI * kHid, 4);
  float* Cg2    = (float*)alloc((size_t)kCap * kOut, 4);
  float* sentb  = (float*)alloc((size_t)kB * kS * kEmb, 4);
  float* uttb   = (float*)alloc((size_t)kB * kU * kEmb, 4);
  float* sessb  = (float*)alloc((size_t)kB * kEmb, 4);
  float* el     = (float*)alloc((size_t)kN * 4, 4);
  float* er     = (float*)alloc((size_t)kN * 4, 4);
  int*   offs   = (int*)alloc(kN + 1, 4);
  int*   cnt    = (int*)alloc(kN, 4);
  int*   csr    = (int*)alloc(E, 4);
  int*   rmt    = (int*)alloc(kTxtRows, 4);
  int*   rmi    = (int*)alloc(kB * kI, 4);
  int*   rowl   = (int*)alloc(kCap, 4);
  int*   info   = (int*)alloc(16, 4);
  (void)ws_size; (void)n_in; (void)out_size;

  // 1) mega prep: transposes, img cvt, sent, rowmap, zeroing (NO wal/war here)
  constexpr int kPrepBlocks = 320 + 2048 + 1024 + 1024 + 512 + 512 + 256 + 34 + 34 + 256 + 128 + 60;
  k_prep0<<<kPrepBlocks, 256, 0, stream>>>(
      text_fc_w, wtTx, image_fc_w, wtIm, gat0_fc, wtG0, gat1_fc, wtG1, gat2_fc, wtG2,
      image_feats, imgbf, sentences, sent_mask, word_embed, sentb, rmt, rmi,
      cnt, Cimg, Cg2);

  // 2) utt + sess + wal/war (parallel)
  k_utt_sess<<<kB * kU + kB + 256, 256, 0, stream>>>(
      utterances, utt_mask, sentb, uttb, sessb,
      gat0_fc, gat1_fc, gat0_al, gat0_ar, gat1_al, gat1_ar, wtG0, wtG1);

  // 3) txt gather + edge count
  k_txtcount<<<kTxtRows + (E + 255) / 256, 256, 0, stream>>>(
      all_words, word_embed, sentb, uttb, sessb, txtbf, edge_dst, cnt, E);

  // 4) scan (also re-zeros cnt)   5) fill
  k_scan<<<1, 1024, 0, stream>>>(cnt, offs, kN);
  k_fill<<<(E + 255) / 256, 256, 0, stream>>>(edge_src, edge_dst, offs, cnt, csr, E);

  auto mmGrid = [](int M, int NcB_) {
    int nrt = (M + 127) / 128;
    return 8 * (NcB_ / 128) * ((nrt + 7) / 8);
  };

  // 6) text FC
  k_mm2<true, false><<<mmGrid(kTxtRows, kHid), 512, 0, stream>>>(
      txtbf, wtTx, text_fc_b, rmt, Abf, nullptr, nullptr, kTxtRows, kEmbPad, kHid, kHid);

  // 7-8) image FC via split-K
  k_mm_sk<<<dim3(kHid / 64, kB * kI / 64, 4), 256, 0, stream>>>(
      imgbf, wtIm, nullptr, Cimg, kB * kI, 2048, kHid, 512);
  k_sk_epi<<<(kB * kI * kHid + 255) / 256, 256, 0, stream>>>(
      Cimg, image_fc_b, rmi, Abf, kB * kI, kHid);

  // 9-10) GAT layer 0 (GEMM with fused el/er cols) + head-sliced aggregation
  k_mm2<true, true><<<mmGrid(kN, kNcB), 512, 0, stream>>>(
      Abf, wtG0, nullptr, nullptr, fbf, el, er, kN, kHid, kNcB, kHid);
  k_agg3h<<<8 * kNBhi, 256, 0, stream>>>(fbf, el, er, offs, csr, gat0_b, Abf);

  // 11-12) GAT layer 1
  k_mm2<true, true><<<mmGrid(kN, kNcB), 512, 0, stream>>>(
      Abf, wtG1, nullptr, nullptr, fbf, el, er, kN, kHid, kNcB, kHid);
  k_agg3h<<<8 * kNBhi, 256, 0, stream>>>(fbf, el, er, offs, csr, gat1_b, Abf);

  // 13-15) GAT layer 2, sparse (rows + GEMM + fused el/er+finish)
  k_rows2<<<1, 256, 0, stream>>>(session_ids, offs, csr, rowl, info);
  k_mm_sk<<<dim3(kOut / 64, kCap / 64, 4), 256, 0, stream>>>(
      Abf, wtG2, rowl, Cg2, kCap, kHid, kOut, 256);
  k_gat2fin<<<kB, 256, 0, stream>>>(Cg2, gat2_al, gat2_ar, info, gat2_b, (float*)d_out);
}